// Round 7
// baseline (164.656 us; speedup 1.0000x reference)
//
#include <hip/hip_runtime.h>
#include <stdint.h>
#include <stddef.h>

typedef _Float16 f16;
typedef __attribute__((ext_vector_type(8))) _Float16 f16x8;
typedef __attribute__((ext_vector_type(4))) _Float16 f16x4;
typedef __attribute__((ext_vector_type(16))) float f32x16;
typedef __attribute__((ext_vector_type(4))) float floatx4;

#define MFMA(a, b, c) __builtin_amdgcn_mfma_f32_32x32x16_f16((a), (b), (c), 0, 0, 0)

typedef const __attribute__((address_space(1))) void gvoid_t;
typedef __attribute__((address_space(3))) void svoid_t;

__device__ __forceinline__ void gload_lds16(const void* g, void* l) {
  // wave-uniform LDS base; HW writes lane's 16B at base + lane*16
  __builtin_amdgcn_global_load_lds((gvoid_t*)g, (svoid_t*)l, 16, 0, 0);
}

// ---------------- all weight transposes in one kernel ----------------
__global__ __launch_bounds__(256) void k_wtrans(const float* __restrict__ W0,
                                                const float* __restrict__ W1,
                                                const float* __restrict__ W2,
                                                const float* __restrict__ W3,
                                                const float* __restrict__ W4,
                                                const float* __restrict__ Wo,
                                                f16* __restrict__ Wth,
                                                f16* __restrict__ Woth) {
  __shared__ float t[32][33];
  int bid = blockIdx.x;
  const float* W;
  f16* Wt;
  int K, N, k0, n0;
  if (bid < 640) {
    int w = bid >> 7, tt = bid & 127;
    W = (w == 0) ? W0 : (w == 1) ? W1 : (w == 2) ? W2 : (w == 3) ? W3 : W4;
    Wt = Wth + (size_t)w * 128 * 1024;
    K = 1024; N = 128;
    k0 = (tt & 31) * 32; n0 = (tt >> 5) * 32;
  } else {
    int tt = bid - 640;
    W = Wo; Wt = Woth;
    K = 128; N = 1024;
    k0 = (tt & 3) * 32; n0 = (tt >> 2) * 32;
  }
  int tx = threadIdx.x & 31, ty = threadIdx.x >> 5;  // 32 x 8
#pragma unroll
  for (int i = 0; i < 4; ++i)
    t[ty + 8 * i][tx] = W[(size_t)(k0 + ty + 8 * i) * N + n0 + tx];
  __syncthreads();
#pragma unroll
  for (int i = 0; i < 4; ++i)
    Wt[(size_t)(n0 + ty + 8 * i) * K + k0 + tx] = (f16)t[tx][ty + 8 * i];
}

// ---------------- projection GEMM: fp32 x, fused cvt, double-buffered pipeline ----------------
// A staged via regs: global block sslot (linear) -> LDS slot sslot^srow (conflict-free
// write, SAME final layout as the proven gload path: slot t holds block t^(r&7)).
// Per K-step: issue B gload(t+1)->buf^1 + A reg-load(t+1) BEFORE MFMAs(t); cvt+write after.
__global__ __launch_bounds__(256, 2) void k_proj(const float* __restrict__ X,
                                                 const f16* __restrict__ Bt,
                                                 const float* __restrict__ cosp,
                                                 const float* __restrict__ sinp,
                                                 f16* __restrict__ q1h, f16* __restrict__ q2h,
                                                 f16* __restrict__ k1h, f16* __restrict__ k2h,
                                                 f16* __restrict__ vh) {
  __shared__ __align__(16) f16 As[2][128 * 64];
  __shared__ __align__(16) f16 Bs[2][128 * 64];
  int bid = blockIdx.x;
  int c8 = bid & 7, tt = bid >> 3;         // tt in 0..79
  int n0 = tt % 5;                         // matrix id
  int m0 = (c8 + 8 * (tt / 5)) * 128;      // row panel: 5 consecutive turns of XCD c8
  int tid = threadIdx.x;
  int wave = tid >> 6, lane = tid & 63;
  int wm = wave * 32;
  int rl = lane & 31, h = lane >> 5;
  int srow = lane >> 3, sslot = lane & 7;
  int wslot = sslot ^ srow;                // conflict-free A ds_write slot (r&7 == srow)
  const f16* Bmat = Bt + (size_t)n0 * 128 * 1024;

  f32x16 acc[4];
#pragma unroll
  for (int nb = 0; nb < 4; ++nb)
#pragma unroll
    for (int r = 0; r < 16; ++r) acc[nb][r] = 0.f;

  floatx4 pa[4][2];  // prefetched fp32 A: 4 chunks x 8 floats

#define LOADA(k0_) do { _Pragma("unroll") for (int c = 0; c < 4; ++c) { \
    int chunk = c * 4 + wave; int r = chunk * 8 + srow; \
    const float* src = X + (size_t)(m0 + r) * 1024 + (k0_) + sslot * 8; \
    pa[c][0] = *(const floatx4*)src; pa[c][1] = *(const floatx4*)(src + 4); } } while (0)
#define WRITEA(bufi) do { _Pragma("unroll") for (int c = 0; c < 4; ++c) { \
    int chunk = c * 4 + wave; \
    f16x8 w; _Pragma("unroll") for (int e = 0; e < 4; ++e) { \
      w[e] = (f16)pa[c][0][e]; w[e + 4] = (f16)pa[c][1][e]; } \
    *(f16x8*)(As[bufi] + chunk * 512 + srow * 64 + wslot * 8) = w; } } while (0)
#define LOADB(k0_, bufi) do { _Pragma("unroll") for (int c = 0; c < 4; ++c) { \
    int chunk = c * 4 + wave; int r = chunk * 8 + srow; int cb = sslot ^ (r & 7); \
    gload_lds16(Bmat + (size_t)r * 1024 + (k0_) + cb * 8, Bs[bufi] + chunk * 512); } } while (0)

  // prologue: stage K-step 0 into buffer 0
  LOADB(0, 0);
  LOADA(0);
  WRITEA(0);
  __syncthreads();

  for (int t = 0; t < 16; ++t) {
    int cur = t & 1;
    if (t < 15) {
      LOADB(64 * (t + 1), cur ^ 1);  // async direct-to-LDS, other buffer
      LOADA(64 * (t + 1));           // fp32 -> regs, latency hidden under MFMAs
    }
#pragma unroll
    for (int kb = 0; kb < 4; ++kb) {
      int s = 2 * kb + h;
      int ra = wm + rl;
      f16x8 af = *(const f16x8*)(As[cur] + ra * 64 + (s ^ (ra & 7)) * 8);
      f16x8 bf[4];
#pragma unroll
      for (int nb = 0; nb < 4; ++nb) {
        int rb2 = nb * 32 + rl;
        bf[nb] = *(const f16x8*)(Bs[cur] + rb2 * 64 + (s ^ (rb2 & 7)) * 8);
      }
#pragma unroll
      for (int nb = 0; nb < 4; ++nb) acc[nb] = MFMA(af, bf[nb], acc[nb]);
    }
    if (t < 15) WRITEA(cur ^ 1);
    __syncthreads();  // drains B gloads (vmcnt) + A ds_writes (lgkm) for next step
  }
#undef LOADA
#undef WRITEA
#undef LOADB

  if (n0 == 4) {  // V: plain cvt store
#pragma unroll
    for (int r = 0; r < 16; ++r) {
      int irow = (r & 3) + 8 * (r >> 2) + 4 * h;
      int gr = m0 + wm + irow;
#pragma unroll
      for (int nb = 0; nb < 4; ++nb)
        vh[(size_t)gr * 128 + nb * 32 + rl] = (f16)acc[nb][r];
    }
  } else {
    f16* outp = (n0 == 0) ? q1h : (n0 == 1) ? q2h : (n0 == 2) ? k1h : k2h;
#pragma unroll
    for (int r = 0; r < 16; ++r) {
      int irow = (r & 3) + 8 * (r >> 2) + 4 * h;
      int gr = m0 + wm + irow;
      int s = gr & 4095;
#pragma unroll
      for (int nb = 0; nb < 2; ++nb) {
        int d = nb * 32 + rl;
        float c = cosp[s * 64 + d], sn = sinp[s * 64 + d];
        float a = acc[nb][r], bb = acc[nb + 2][r];
        outp[(size_t)gr * 128 + d]      = (f16)(a * c - bb * sn);
        outp[(size_t)gr * 128 + 64 + d] = (f16)(a * sn + bb * c);
      }
    }
  }
}

// ---------------- V transpose (f16): vh(16384x128) -> vt[b][d][s] ----------------
__global__ __launch_bounds__(256) void k_vtrans16(const f16* __restrict__ vh,
                                                  f16* __restrict__ vt) {
  __shared__ unsigned short t[32][33];
  int r0 = blockIdx.x * 32, d0 = blockIdx.y * 32;
  int tx = threadIdx.x & 31, ty = threadIdx.x >> 5;
#pragma unroll
  for (int i = 0; i < 4; ++i)
    t[ty + 8 * i][tx] = ((const unsigned short*)vh)[(size_t)(r0 + ty + 8 * i) * 128 + d0 + tx];
  __syncthreads();
  int b = r0 >> 12, s0 = r0 & 4095;
#pragma unroll
  for (int i = 0; i < 4; ++i)
    ((unsigned short*)vt)[((size_t)(b * 128 + d0 + ty + 8 * i)) * 4096 + s0 + tx] =
        t[tx][ty + 8 * i];
}

// ---------------- S-phase: P = mask(S1*S2)/128, packed lower-triangle tiles ----------------
__global__ __launch_bounds__(256, 2) void k_s(const f16* __restrict__ q1h,
                                              const f16* __restrict__ q2h,
                                              const f16* __restrict__ k1h,
                                              const f16* __restrict__ k2h,
                                              f16* __restrict__ P) {
  __shared__ __align__(16) f16 A1[128 * 64];
  __shared__ __align__(16) f16 A2[128 * 64];
  __shared__ __align__(16) f16 B1[128 * 64];
  __shared__ __align__(16) f16 B2[128 * 64];
  int bid0 = blockIdx.x;
  int bid = (bid0 & 7) * 264 + (bid0 >> 3);  // XCD-contiguous chunks (2112 = 8*264)
  int b = bid / 528, t = bid % 528;
  int i = (int)((sqrtf(8.f * t + 1.f) - 1.f) * 0.5f);
  if ((i + 1) * (i + 2) / 2 <= t) ++i;
  if (i * (i + 1) / 2 > t) --i;
  int j = t - i * (i + 1) / 2;

  int tid = threadIdx.x;
  int wave = tid >> 6, lane = tid & 63;
  int wm = (wave >> 1) * 64, wn = (wave & 1) * 64;
  int rl = lane & 31, h = lane >> 5;
  int srow = lane >> 3, sslot = lane & 7;
  size_t rowA = (size_t)b * 4096 + i * 128;
  size_t rowB = (size_t)b * 4096 + j * 128;

  f32x16 acc1[2][2], acc2[2][2];
#pragma unroll
  for (int mb = 0; mb < 2; ++mb)
#pragma unroll
    for (int nb = 0; nb < 2; ++nb)
#pragma unroll
      for (int r = 0; r < 16; ++r) { acc1[mb][nb][r] = 0.f; acc2[mb][nb][r] = 0.f; }

  for (int k0 = 0; k0 < 128; k0 += 64) {
    __syncthreads();
#pragma unroll
    for (int c = 0; c < 4; ++c) {
      int chunk = c * 4 + wave;
      int r = chunk * 8 + srow;
      int cb = sslot ^ (r & 7);
      gload_lds16(q1h + (rowA + r) * 128 + k0 + cb * 8, A1 + chunk * 512);
      gload_lds16(q2h + (rowA + r) * 128 + k0 + cb * 8, A2 + chunk * 512);
      gload_lds16(k1h + (rowB + r) * 128 + k0 + cb * 8, B1 + chunk * 512);
      gload_lds16(k2h + (rowB + r) * 128 + k0 + cb * 8, B2 + chunk * 512);
    }
    __syncthreads();

#pragma unroll
    for (int kb = 0; kb < 4; ++kb) {
      int s = 2 * kb + h;
      f16x8 a1f[2], a2f[2], b1f[2], b2f[2];
#pragma unroll
      for (int mb = 0; mb < 2; ++mb) {
        int r = wm + mb * 32 + rl;
        int off = r * 64 + (s ^ (r & 7)) * 8;
        a1f[mb] = *(const f16x8*)(A1 + off);
        a2f[mb] = *(const f16x8*)(A2 + off);
      }
#pragma unroll
      for (int nb = 0; nb < 2; ++nb) {
        int r = wn + nb * 32 + rl;
        int off = r * 64 + (s ^ (r & 7)) * 8;
        b1f[nb] = *(const f16x8*)(B1 + off);
        b2f[nb] = *(const f16x8*)(B2 + off);
      }
#pragma unroll
      for (int mb = 0; mb < 2; ++mb)
#pragma unroll
        for (int nb = 0; nb < 2; ++nb) {
          acc1[mb][nb] = MFMA(a1f[mb], b1f[nb], acc1[mb][nb]);
          acc2[mb][nb] = MFMA(a2f[mb], b2f[nb], acc2[mb][nb]);
        }
    }
  }

  f16* pt = P + ((size_t)b * 528 + t) * 16384;
  bool diag = (i == j);
#pragma unroll
  for (int mb = 0; mb < 2; ++mb)
#pragma unroll
    for (int nb = 0; nb < 2; ++nb)
#pragma unroll
      for (int r = 0; r < 16; ++r) {
        int row_l = wm + mb * 32 + (r & 3) + 8 * (r >> 2) + 4 * h;
        int col_l = wn + nb * 32 + rl;
        float p = acc1[mb][nb][r] * acc2[mb][nb][r] * (1.0f / 128.0f);
        if (diag && col_l > row_l) p = 0.f;
        pt[(size_t)row_l * 128 + col_l] = (f16)p;
      }
}

// ---------------- PV-phase: O_partial = P_packed * V^T, split-K over 512-key chunks ----------------
// per batch: qt 0..31, splits = qt/4+1 (512-key chunks), 144 blocks; 576 total.
__global__ __launch_bounds__(256, 2) void k_pv(const f16* __restrict__ P,
                                               const f16* __restrict__ vt,
                                               f16* __restrict__ obase) {
  __shared__ __align__(16) f16 As[128 * 64];
  __shared__ __align__(16) f16 Bs[128 * 64];
  int bid = blockIdx.x;
  int b = bid / 144, c = bid % 144;
  int g = (int)((sqrtf(2.f * c + 1.f) - 1.f) * 0.5f);
  while (2 * (g + 1) * (g + 2) <= c) ++g;
  while (2 * g * (g + 1) > c) --g;
  int off = c - 2 * g * (g + 1);
  int qt = g * 4 + off / (g + 1);
  int s = off - (off / (g + 1)) * (g + 1);
  int tq = qt * (qt + 1) / 2;
  const f16* Pb = P + (size_t)b * 528 * 16384;
  const f16* vb = vt + (size_t)b * 128 * 4096;
  int kbase = s * 512;
  int kend = (qt + 1) * 128 < kbase + 512 ? (qt + 1) * 128 : kbase + 512;

  int tid = threadIdx.x;
  int wave = tid >> 6, lane = tid & 63;
  int wm = (wave >> 1) * 64, wn = (wave & 1) * 64;
  int rl = lane & 31, h = lane >> 5;
  int srow = lane >> 3, sslot = lane & 7;

  f32x16 acc[2][2];
#pragma unroll
  for (int mb = 0; mb < 2; ++mb)
#pragma unroll
    for (int nb = 0; nb < 2; ++nb)
#pragma unroll
      for (int r = 0; r < 16; ++r) acc[mb][nb][r] = 0.f;

  for (int k0 = kbase; k0 < kend; k0 += 64) {
    int jt = k0 >> 7, koff = k0 & 127;
    const f16* Pt = Pb + (size_t)(tq + jt) * 16384;
    __syncthreads();
#pragma unroll
    for (int c4 = 0; c4 < 4; ++c4) {
      int chunk = c4 * 4 + wave;
      int r = chunk * 8 + srow;
      int cb = sslot ^ (r & 7);
      gload_lds16(Pt + (size_t)r * 128 + koff + cb * 8, As + chunk * 512);
      gload_lds16(vb + (size_t)r * 4096 + k0 + cb * 8, Bs + chunk * 512);
    }
    __syncthreads();

#pragma unroll
    for (int kb = 0; kb < 4; ++kb) {
      int sidx = 2 * kb + h;
      f16x8 af[2], bf[2];
#pragma unroll
      for (int mb = 0; mb < 2; ++mb) {
        int r = wm + mb * 32 + rl;
        af[mb] = *(const f16x8*)(As + r * 64 + (sidx ^ (r & 7)) * 8);
      }
#pragma unroll
      for (int nb = 0; nb < 2; ++nb) {
        int r = wn + nb * 32 + rl;
        bf[nb] = *(const f16x8*)(Bs + r * 64 + (sidx ^ (r & 7)) * 8);
      }
#pragma unroll
      for (int mb = 0; mb < 2; ++mb)
#pragma unroll
        for (int nb = 0; nb < 2; ++nb)
          acc[mb][nb] = MFMA(af[mb], bf[nb], acc[mb][nb]);
    }
  }

  f16* op = obase + (size_t)s * 2097152;
#pragma unroll
  for (int mb = 0; mb < 2; ++mb)
#pragma unroll
    for (int nb = 0; nb < 2; ++nb)
#pragma unroll
      for (int r = 0; r < 16; ++r) {
        int gr = b * 4096 + qt * 128 + wm + mb * 32 + (r & 3) + 8 * (r >> 2) + 4 * h;
        op[(size_t)gr * 128 + wn + nb * 32 + rl] = (f16)acc[mb][nb][r];
      }
}

// ---------------- output projection with fused partial-combine A staging ----------------
// C(16384x1024 fp32) = (sum_s o_s)(16384x128) * Woth(1024x128)^T
__global__ __launch_bounds__(256, 2) void k_gout(const f16* __restrict__ obase,
                                                 const f16* __restrict__ Bt,
                                                 float* __restrict__ C) {
  __shared__ __align__(16) f16 As[128 * 64];
  __shared__ __align__(16) f16 Bs[128 * 64];
  int tid = threadIdx.x;
  int wave = tid >> 6, lane = tid & 63;
  int m0 = blockIdx.y * 128, n0 = blockIdx.x * 128;
  int wm = (wave >> 1) * 64, wn = (wave & 1) * 64;
  int rl = lane & 31, h = lane >> 5;
  int srow = lane >> 3, sslot = lane & 7;
  int qt = (m0 >> 7) & 31;
  int ns = (qt >> 2) + 1;  // number of PV split partials covering this row block

  f32x16 acc[2][2];
#pragma unroll
  for (int mb = 0; mb < 2; ++mb)
#pragma unroll
    for (int nb = 0; nb < 2; ++nb)
#pragma unroll
      for (int r = 0; r < 16; ++r) acc[mb][nb][r] = 0.f;

  for (int k0 = 0; k0 < 128; k0 += 64) {
    __syncthreads();
#pragma unroll
    for (int c = 0; c < 4; ++c) {
      int chunk = c * 4 + wave;
      int r = chunk * 8 + srow;
      // A: reg-stage sum of partials, swizzled ds_write
      float sum[8];
#pragma unroll
      for (int e = 0; e < 8; ++e) sum[e] = 0.f;
#pragma unroll
      for (int p = 0; p < 8; ++p) {
        if (p < ns) {
          f16x8 v = *(const f16x8*)(obase + (size_t)p * 2097152 +
                                    (size_t)(m0 + r) * 128 + k0 + sslot * 8);
#pragma unroll
          for (int e = 0; e < 8; ++e) sum[e] += (float)v[e];
        }
      }
      f16x8 w;
#pragma unroll
      for (int e = 0; e < 8; ++e) w[e] = (f16)sum[e];
      *(f16x8*)(As + r * 64 + (sslot ^ (r & 7)) * 8) = w;
      // B: async stage
      int cb = sslot ^ (r & 7);
      gload_lds16(Bt + (size_t)(n0 + r) * 128 + k0 + cb * 8, Bs + chunk * 512);
    }
    __syncthreads();

#pragma unroll
    for (int kb = 0; kb < 4; ++kb) {
      int s = 2 * kb + h;
      f16x8 af[2], bf[2];
#pragma unroll
      for (int mb = 0; mb < 2; ++mb) {
        int r = wm + mb * 32 + rl;
        af[mb] = *(const f16x8*)(As + r * 64 + (s ^ (r & 7)) * 8);
      }
#pragma unroll
      for (int nb = 0; nb < 2; ++nb) {
        int r = wn + nb * 32 + rl;
        bf[nb] = *(const f16x8*)(Bs + r * 64 + (s ^ (r & 7)) * 8);
      }
#pragma unroll
      for (int mb = 0; mb < 2; ++mb)
#pragma unroll
        for (int nb = 0; nb < 2; ++nb)
          acc[mb][nb] = MFMA(af[mb], bf[nb], acc[mb][nb]);
    }
  }

#pragma unroll
  for (int mb = 0; mb < 2; ++mb)
#pragma unroll
    for (int nb = 0; nb < 2; ++nb)
#pragma unroll
      for (int r = 0; r < 16; ++r) {
        int i = m0 + wm + mb * 32 + (r & 3) + 8 * (r >> 2) + 4 * h;
        int j = n0 + wn + nb * 32 + rl;
        C[(size_t)i * 1024 + j] = acc[mb][nb][r];
      }
}

// ---------------- launch ----------------
extern "C" void kernel_launch(void* const* d_in, const int* in_sizes, int n_in,
                              void* d_out, int out_size, void* d_ws, size_t ws_size,
                              hipStream_t stream) {
  (void)in_sizes; (void)n_in; (void)out_size; (void)ws_size;
  const float* x  = (const float*)d_in[0];
  const float* cp = (const float*)d_in[1];
  const float* sp = (const float*)d_in[2];
  // d_in[3] = causal_mask (unused; mask computed analytically)
  const float* W[5] = {(const float*)d_in[4], (const float*)d_in[5], (const float*)d_in[6],
                       (const float*)d_in[7], (const float*)d_in[8]};
  const float* Wo = (const float*)d_in[9];
  float* out = (float*)d_out;
  char* ws = (char*)d_ws;

  // workspace layout (bytes):
  // [0, 32M): 8 x f16 PV partials (4 MB each)
  // [32M, 56M): q1h,q2h,k1h,k2h,vh,vt (4 MB each); then Wth (1.25M), Woth (0.25M), P (69M)
  const size_t OFF_H    = 33554432;
  const size_t OFF_WTH  = OFF_H + 6 * 4194304;
  const size_t OFF_WOTH = OFF_WTH + 1310720;
  const size_t OFF_P    = OFF_WOTH + 262144;
  f16*   obase = (f16*)(ws + 0);
  f16*   q1h  = (f16*)(ws + OFF_H + 0 * 4194304);
  f16*   q2h  = (f16*)(ws + OFF_H + 1 * 4194304);
  f16*   k1h  = (f16*)(ws + OFF_H + 2 * 4194304);
  f16*   k2h  = (f16*)(ws + OFF_H + 3 * 4194304);
  f16*   vh   = (f16*)(ws + OFF_H + 4 * 4194304);
  f16*   vt   = (f16*)(ws + OFF_H + 5 * 4194304);
  f16*   Wth  = (f16*)(ws + OFF_WTH);
  f16*   Woth = (f16*)(ws + OFF_WOTH);
  f16*   P    = (f16*)(ws + OFF_P);

  // 1) all weight transposes (one kernel)
  k_wtrans<<<768, 256, 0, stream>>>(W[0], W[1], W[2], W[3], W[4], Wo, Wth, Woth);
  // 2) projections from fp32 x (pipelined fused-cvt staging, XCD-grouped) + fused RoPE
  k_proj<<<640, 256, 0, stream>>>(x, Wth, cp, sp, q1h, q2h, k1h, k2h, vh);
  // 3) V transpose
  k_vtrans16<<<dim3(512, 4), 256, 0, stream>>>(vh, vt);
  // 4) S-phase (packed triangular P)
  k_s<<<2112, 256, 0, stream>>>(q1h, q2h, k1h, k2h, P);
  // 5) PV-phase (split-K f16 partials, 512-key chunks)
  k_pv<<<576, 256, 0, stream>>>(P, vt, obase);
  // 6) output projection with fused partial combine
  k_gout<<<dim3(8, 128), 256, 0, stream>>>(obase, Woth, out);
}

// Round 8
// 149.153 us; speedup vs baseline: 1.1039x; 1.1039x over previous
//
#include <hip/hip_runtime.h>
#include <stdint.h>
#include <stddef.h>

typedef _Float16 f16;
typedef __attribute__((ext_vector_type(8))) _Float16 f16x8;
typedef __attribute__((ext_vector_type(4))) _Float16 f16x4;
typedef __attribute__((ext_vector_type(16))) float f32x16;
typedef __attribute__((ext_vector_type(4))) float floatx4;

#define MFMA(a, b, c) __builtin_amdgcn_mfma_f32_32x32x16_f16((a), (b), (c), 0, 0, 0)

typedef const __attribute__((address_space(1))) void gvoid_t;
typedef __attribute__((address_space(3))) void svoid_t;

__device__ __forceinline__ void gload_lds16(const void* g, void* l) {
  // wave-uniform LDS base; HW writes lane's 16B at base + lane*16
  __builtin_amdgcn_global_load_lds((gvoid_t*)g, (svoid_t*)l, 16, 0, 0);
}

// ---------------- prep: x fp32->f16 cvt + all weight transposes, one dispatch ----------------
// blocks [0, 16384): cvt xh; [16384, 17024): Wq1,Wq2,Wk1,Wk2,Wv transpose; [17024, 17152): Wo.
__global__ __launch_bounds__(256) void k_prep(const float* __restrict__ x,
                                              const float* __restrict__ W0,
                                              const float* __restrict__ W1,
                                              const float* __restrict__ W2,
                                              const float* __restrict__ W3,
                                              const float* __restrict__ W4,
                                              const float* __restrict__ Wo,
                                              f16* __restrict__ xh,
                                              f16* __restrict__ Wth,
                                              f16* __restrict__ Woth) {
  __shared__ float t[32][33];
  int bid = blockIdx.x;
  if (bid < 16384) {  // x -> f16, vectorized
    int i = bid * 256 + threadIdx.x;
    floatx4 v = ((const floatx4*)x)[i];
    f16x4 o;
    o[0] = (f16)v[0]; o[1] = (f16)v[1]; o[2] = (f16)v[2]; o[3] = (f16)v[3];
    ((f16x4*)xh)[i] = o;
    return;
  }
  const float* W;
  f16* Wt;
  int K, N, k0, n0;
  if (bid < 17024) {
    int b2 = bid - 16384;
    int w = b2 >> 7, tt = b2 & 127;
    W = (w == 0) ? W0 : (w == 1) ? W1 : (w == 2) ? W2 : (w == 3) ? W3 : W4;
    Wt = Wth + (size_t)w * 128 * 1024;
    K = 1024; N = 128;
    k0 = (tt & 31) * 32; n0 = (tt >> 5) * 32;
  } else {
    int tt = bid - 17024;
    W = Wo; Wt = Woth;
    K = 128; N = 1024;
    k0 = (tt & 3) * 32; n0 = (tt >> 2) * 32;
  }
  int tx = threadIdx.x & 31, ty = threadIdx.x >> 5;  // 32 x 8
#pragma unroll
  for (int i = 0; i < 4; ++i)
    t[ty + 8 * i][tx] = W[(size_t)(k0 + ty + 8 * i) * N + n0 + tx];
  __syncthreads();
#pragma unroll
  for (int i = 0; i < 4; ++i)
    Wt[(size_t)(n0 + ty + 8 * i) * K + k0 + tx] = (f16)t[tx][ty + 8 * i];
}

// ---------------- projection GEMM (f16 A via gload_lds), XCD-group swizzle, fused RoPE ----------------
// Round-5 proven form: A = xh (16384x1024 f16), Bt = Wth (5 matrices of 128x1024 f16).
// 1-D grid of 640; bid mapping puts the 5 matrix-blocks of one 128-row x-panel
// on the SAME XCD in adjacent issue slots -> panel served from that XCD's L2.
__global__ __launch_bounds__(256, 2) void k_proj(const f16* __restrict__ A,
                                                 const f16* __restrict__ Bt,
                                                 const float* __restrict__ cosp,
                                                 const float* __restrict__ sinp,
                                                 f16* __restrict__ q1h, f16* __restrict__ q2h,
                                                 f16* __restrict__ k1h, f16* __restrict__ k2h,
                                                 f16* __restrict__ vh) {
  __shared__ __align__(16) f16 As[128 * 64];
  __shared__ __align__(16) f16 Bs[128 * 64];
  int bid = blockIdx.x;
  int c8 = bid & 7, t = bid >> 3;          // t in 0..79
  int n0 = t % 5;                          // matrix id
  int m0 = (c8 + 8 * (t / 5)) * 128;       // row panel: 5 consecutive turns of XCD c8
  int tid = threadIdx.x;
  int wave = tid >> 6, lane = tid & 63;
  int wm = wave * 32;
  int rl = lane & 31, h = lane >> 5;
  int srow = lane >> 3, sslot = lane & 7;
  const f16* Bmat = Bt + (size_t)n0 * 128 * 1024;

  f32x16 acc[4];
#pragma unroll
  for (int nb = 0; nb < 4; ++nb)
#pragma unroll
    for (int r = 0; r < 16; ++r) acc[nb][r] = 0.f;

  for (int k0 = 0; k0 < 1024; k0 += 64) {
    __syncthreads();
#pragma unroll
    for (int c = 0; c < 4; ++c) {
      int chunk = c * 4 + wave;
      int r = chunk * 8 + srow;
      int cb = sslot ^ (r & 7);
      gload_lds16(A + (size_t)(m0 + r) * 1024 + k0 + cb * 8, As + chunk * 512);
      gload_lds16(Bmat + (size_t)r * 1024 + k0 + cb * 8, Bs + chunk * 512);
    }
    __syncthreads();

#pragma unroll
    for (int kb = 0; kb < 4; ++kb) {
      int s = 2 * kb + h;
      int ra = wm + rl;
      f16x8 af = *(const f16x8*)(As + ra * 64 + (s ^ (ra & 7)) * 8);
      f16x8 bf[4];
#pragma unroll
      for (int nb = 0; nb < 4; ++nb) {
        int rb = nb * 32 + rl;
        bf[nb] = *(const f16x8*)(Bs + rb * 64 + (s ^ (rb & 7)) * 8);
      }
#pragma unroll
      for (int nb = 0; nb < 4; ++nb) acc[nb] = MFMA(af, bf[nb], acc[nb]);
    }
  }

  if (n0 == 4) {  // V: plain cvt store
#pragma unroll
    for (int r = 0; r < 16; ++r) {
      int irow = (r & 3) + 8 * (r >> 2) + 4 * h;
      int gr = m0 + wm + irow;
#pragma unroll
      for (int nb = 0; nb < 4; ++nb)
        vh[(size_t)gr * 128 + nb * 32 + rl] = (f16)acc[nb][r];
    }
  } else {
    f16* outp = (n0 == 0) ? q1h : (n0 == 1) ? q2h : (n0 == 2) ? k1h : k2h;
#pragma unroll
    for (int r = 0; r < 16; ++r) {
      int irow = (r & 3) + 8 * (r >> 2) + 4 * h;
      int gr = m0 + wm + irow;
      int s = gr & 4095;
#pragma unroll
      for (int nb = 0; nb < 2; ++nb) {
        int d = nb * 32 + rl;
        float c = cosp[s * 64 + d], sn = sinp[s * 64 + d];
        float a = acc[nb][r], bb = acc[nb + 2][r];
        outp[(size_t)gr * 128 + d]      = (f16)(a * c - bb * sn);
        outp[(size_t)gr * 128 + 64 + d] = (f16)(a * sn + bb * c);
      }
    }
  }
}

// ---------------- V transpose (f16): vh(16384x128) -> vt[b][d][s] ----------------
__global__ __launch_bounds__(256) void k_vtrans16(const f16* __restrict__ vh,
                                                  f16* __restrict__ vt) {
  __shared__ unsigned short t[32][33];
  int r0 = blockIdx.x * 32, d0 = blockIdx.y * 32;
  int tx = threadIdx.x & 31, ty = threadIdx.x >> 5;
#pragma unroll
  for (int i = 0; i < 4; ++i)
    t[ty + 8 * i][tx] = ((const unsigned short*)vh)[(size_t)(r0 + ty + 8 * i) * 128 + d0 + tx];
  __syncthreads();
  int b = r0 >> 12, s0 = r0 & 4095;
#pragma unroll
  for (int i = 0; i < 4; ++i)
    ((unsigned short*)vt)[((size_t)(b * 128 + d0 + ty + 8 * i)) * 4096 + s0 + tx] =
        t[tx][ty + 8 * i];
}

// ---------------- S-phase: P = mask(S1*S2)/128, packed lower-triangle tiles ----------------
__global__ __launch_bounds__(256, 2) void k_s(const f16* __restrict__ q1h,
                                              const f16* __restrict__ q2h,
                                              const f16* __restrict__ k1h,
                                              const f16* __restrict__ k2h,
                                              f16* __restrict__ P) {
  __shared__ __align__(16) f16 A1[128 * 64];
  __shared__ __align__(16) f16 A2[128 * 64];
  __shared__ __align__(16) f16 B1[128 * 64];
  __shared__ __align__(16) f16 B2[128 * 64];
  int bid0 = blockIdx.x;
  int bid = (bid0 & 7) * 264 + (bid0 >> 3);  // XCD-contiguous chunks (2112 = 8*264)
  int b = bid / 528, t = bid % 528;
  int i = (int)((sqrtf(8.f * t + 1.f) - 1.f) * 0.5f);
  if ((i + 1) * (i + 2) / 2 <= t) ++i;
  if (i * (i + 1) / 2 > t) --i;
  int j = t - i * (i + 1) / 2;

  int tid = threadIdx.x;
  int wave = tid >> 6, lane = tid & 63;
  int wm = (wave >> 1) * 64, wn = (wave & 1) * 64;
  int rl = lane & 31, h = lane >> 5;
  int srow = lane >> 3, sslot = lane & 7;
  size_t rowA = (size_t)b * 4096 + i * 128;
  size_t rowB = (size_t)b * 4096 + j * 128;

  f32x16 acc1[2][2], acc2[2][2];
#pragma unroll
  for (int mb = 0; mb < 2; ++mb)
#pragma unroll
    for (int nb = 0; nb < 2; ++nb)
#pragma unroll
      for (int r = 0; r < 16; ++r) { acc1[mb][nb][r] = 0.f; acc2[mb][nb][r] = 0.f; }

  for (int k0 = 0; k0 < 128; k0 += 64) {
    __syncthreads();
#pragma unroll
    for (int c = 0; c < 4; ++c) {
      int chunk = c * 4 + wave;
      int r = chunk * 8 + srow;
      int cb = sslot ^ (r & 7);
      gload_lds16(q1h + (rowA + r) * 128 + k0 + cb * 8, A1 + chunk * 512);
      gload_lds16(q2h + (rowA + r) * 128 + k0 + cb * 8, A2 + chunk * 512);
      gload_lds16(k1h + (rowB + r) * 128 + k0 + cb * 8, B1 + chunk * 512);
      gload_lds16(k2h + (rowB + r) * 128 + k0 + cb * 8, B2 + chunk * 512);
    }
    __syncthreads();

#pragma unroll
    for (int kb = 0; kb < 4; ++kb) {
      int s = 2 * kb + h;
      f16x8 a1f[2], a2f[2], b1f[2], b2f[2];
#pragma unroll
      for (int mb = 0; mb < 2; ++mb) {
        int r = wm + mb * 32 + rl;
        int off = r * 64 + (s ^ (r & 7)) * 8;
        a1f[mb] = *(const f16x8*)(A1 + off);
        a2f[mb] = *(const f16x8*)(A2 + off);
      }
#pragma unroll
      for (int nb = 0; nb < 2; ++nb) {
        int r = wn + nb * 32 + rl;
        int off = r * 64 + (s ^ (r & 7)) * 8;
        b1f[nb] = *(const f16x8*)(B1 + off);
        b2f[nb] = *(const f16x8*)(B2 + off);
      }
#pragma unroll
      for (int mb = 0; mb < 2; ++mb)
#pragma unroll
        for (int nb = 0; nb < 2; ++nb) {
          acc1[mb][nb] = MFMA(a1f[mb], b1f[nb], acc1[mb][nb]);
          acc2[mb][nb] = MFMA(a2f[mb], b2f[nb], acc2[mb][nb]);
        }
    }
  }

  f16* pt = P + ((size_t)b * 528 + t) * 16384;
  bool diag = (i == j);
#pragma unroll
  for (int mb = 0; mb < 2; ++mb)
#pragma unroll
    for (int nb = 0; nb < 2; ++nb)
#pragma unroll
      for (int r = 0; r < 16; ++r) {
        int row_l = wm + mb * 32 + (r & 3) + 8 * (r >> 2) + 4 * h;
        int col_l = wn + nb * 32 + rl;
        float p = acc1[mb][nb][r] * acc2[mb][nb][r] * (1.0f / 128.0f);
        if (diag && col_l > row_l) p = 0.f;
        pt[(size_t)row_l * 128 + col_l] = (f16)p;
      }
}

// ---------------- PV-phase: O_partial = P_packed * V^T, split-K over 512-key chunks ----------------
// per batch: qt 0..31, splits = qt/4+1 (512-key chunks), 144 blocks; 576 total.
__global__ __launch_bounds__(256, 2) void k_pv(const f16* __restrict__ P,
                                               const f16* __restrict__ vt,
                                               f16* __restrict__ obase) {
  __shared__ __align__(16) f16 As[128 * 64];
  __shared__ __align__(16) f16 Bs[128 * 64];
  int bid = blockIdx.x;
  int b = bid / 144, c = bid % 144;
  int g = (int)((sqrtf(2.f * c + 1.f) - 1.f) * 0.5f);
  while (2 * (g + 1) * (g + 2) <= c) ++g;
  while (2 * g * (g + 1) > c) --g;
  int off = c - 2 * g * (g + 1);
  int qt = g * 4 + off / (g + 1);
  int s = off - (off / (g + 1)) * (g + 1);
  int tq = qt * (qt + 1) / 2;
  const f16* Pb = P + (size_t)b * 528 * 16384;
  const f16* vb = vt + (size_t)b * 128 * 4096;
  int kbase = s * 512;
  int kend = (qt + 1) * 128 < kbase + 512 ? (qt + 1) * 128 : kbase + 512;

  int tid = threadIdx.x;
  int wave = tid >> 6, lane = tid & 63;
  int wm = (wave >> 1) * 64, wn = (wave & 1) * 64;
  int rl = lane & 31, h = lane >> 5;
  int srow = lane >> 3, sslot = lane & 7;

  f32x16 acc[2][2];
#pragma unroll
  for (int mb = 0; mb < 2; ++mb)
#pragma unroll
    for (int nb = 0; nb < 2; ++nb)
#pragma unroll
      for (int r = 0; r < 16; ++r) acc[mb][nb][r] = 0.f;

  for (int k0 = kbase; k0 < kend; k0 += 64) {
    int jt = k0 >> 7, koff = k0 & 127;
    const f16* Pt = Pb + (size_t)(tq + jt) * 16384;
    __syncthreads();
#pragma unroll
    for (int c4 = 0; c4 < 4; ++c4) {
      int chunk = c4 * 4 + wave;
      int r = chunk * 8 + srow;
      int cb = sslot ^ (r & 7);
      gload_lds16(Pt + (size_t)r * 128 + koff + cb * 8, As + chunk * 512);
      gload_lds16(vb + (size_t)r * 4096 + k0 + cb * 8, Bs + chunk * 512);
    }
    __syncthreads();

#pragma unroll
    for (int kb = 0; kb < 4; ++kb) {
      int sidx = 2 * kb + h;
      f16x8 af[2], bf[2];
#pragma unroll
      for (int mb = 0; mb < 2; ++mb) {
        int r = wm + mb * 32 + rl;
        af[mb] = *(const f16x8*)(As + r * 64 + (sidx ^ (r & 7)) * 8);
      }
#pragma unroll
      for (int nb = 0; nb < 2; ++nb) {
        int r = wn + nb * 32 + rl;
        bf[nb] = *(const f16x8*)(Bs + r * 64 + (sidx ^ (r & 7)) * 8);
      }
#pragma unroll
      for (int mb = 0; mb < 2; ++mb)
#pragma unroll
        for (int nb = 0; nb < 2; ++nb)
          acc[mb][nb] = MFMA(af[mb], bf[nb], acc[mb][nb]);
    }
  }

  f16* op = obase + (size_t)s * 2097152;
#pragma unroll
  for (int mb = 0; mb < 2; ++mb)
#pragma unroll
    for (int nb = 0; nb < 2; ++nb)
#pragma unroll
      for (int r = 0; r < 16; ++r) {
        int gr = b * 4096 + qt * 128 + wm + mb * 32 + (r & 3) + 8 * (r >> 2) + 4 * h;
        op[(size_t)gr * 128 + wn + nb * 32 + rl] = (f16)acc[mb][nb][r];
      }
}

// ---------------- output projection with fused partial-combine A staging ----------------
// C(16384x1024 fp32) = (sum_s o_s)(16384x128) * Woth(1024x128)^T
__global__ __launch_bounds__(256, 2) void k_gout(const f16* __restrict__ obase,
                                                 const f16* __restrict__ Bt,
                                                 float* __restrict__ C) {
  __shared__ __align__(16) f16 As[128 * 64];
  __shared__ __align__(16) f16 Bs[128 * 64];
  int tid = threadIdx.x;
  int wave = tid >> 6, lane = tid & 63;
  int m0 = blockIdx.y * 128, n0 = blockIdx.x * 128;
  int wm = (wave >> 1) * 64, wn = (wave & 1) * 64;
  int rl = lane & 31, h = lane >> 5;
  int srow = lane >> 3, sslot = lane & 7;
  int qt = (m0 >> 7) & 31;
  int ns = (qt >> 2) + 1;  // number of PV split partials covering this row block

  f32x16 acc[2][2];
#pragma unroll
  for (int mb = 0; mb < 2; ++mb)
#pragma unroll
    for (int nb = 0; nb < 2; ++nb)
#pragma unroll
      for (int r = 0; r < 16; ++r) acc[mb][nb][r] = 0.f;

  for (int k0 = 0; k0 < 128; k0 += 64) {
    __syncthreads();
#pragma unroll
    for (int c = 0; c < 4; ++c) {
      int chunk = c * 4 + wave;
      int r = chunk * 8 + srow;
      // A: reg-stage sum of partials, swizzled ds_write
      float sum[8];
#pragma unroll
      for (int e = 0; e < 8; ++e) sum[e] = 0.f;
#pragma unroll
      for (int p = 0; p < 8; ++p) {
        if (p < ns) {
          f16x8 v = *(const f16x8*)(obase + (size_t)p * 2097152 +
                                    (size_t)(m0 + r) * 128 + k0 + sslot * 8);
#pragma unroll
          for (int e = 0; e < 8; ++e) sum[e] += (float)v[e];
        }
      }
      f16x8 w;
#pragma unroll
      for (int e = 0; e < 8; ++e) w[e] = (f16)sum[e];
      *(f16x8*)(As + r * 64 + (sslot ^ (r & 7)) * 8) = w;
      // B: async stage
      int cb = sslot ^ (r & 7);
      gload_lds16(Bt + (size_t)(n0 + r) * 128 + k0 + cb * 8, Bs + chunk * 512);
    }
    __syncthreads();

#pragma unroll
    for (int kb = 0; kb < 4; ++kb) {
      int s = 2 * kb + h;
      f16x8 af[2], bf[2];
#pragma unroll
      for (int mb = 0; mb < 2; ++mb) {
        int r = wm + mb * 32 + rl;
        af[mb] = *(const f16x8*)(As + r * 64 + (s ^ (r & 7)) * 8);
      }
#pragma unroll
      for (int nb = 0; nb < 2; ++nb) {
        int r = wn + nb * 32 + rl;
        bf[nb] = *(const f16x8*)(Bs + r * 64 + (s ^ (r & 7)) * 8);
      }
#pragma unroll
      for (int mb = 0; mb < 2; ++mb)
#pragma unroll
        for (int nb = 0; nb < 2; ++nb)
          acc[mb][nb] = MFMA(af[mb], bf[nb], acc[mb][nb]);
    }
  }

#pragma unroll
  for (int mb = 0; mb < 2; ++mb)
#pragma unroll
    for (int nb = 0; nb < 2; ++nb)
#pragma unroll
      for (int r = 0; r < 16; ++r) {
        int i = m0 + wm + mb * 32 + (r & 3) + 8 * (r >> 2) + 4 * h;
        int j = n0 + wn + nb * 32 + rl;
        C[(size_t)i * 1024 + j] = acc[mb][nb][r];
      }
}

// ---------------- launch ----------------
extern "C" void kernel_launch(void* const* d_in, const int* in_sizes, int n_in,
                              void* d_out, int out_size, void* d_ws, size_t ws_size,
                              hipStream_t stream) {
  (void)in_sizes; (void)n_in; (void)out_size; (void)ws_size;
  const float* x  = (const float*)d_in[0];
  const float* cp = (const float*)d_in[1];
  const float* sp = (const float*)d_in[2];
  // d_in[3] = causal_mask (unused; mask computed analytically)
  const float* W[5] = {(const float*)d_in[4], (const float*)d_in[5], (const float*)d_in[6],
                       (const float*)d_in[7], (const float*)d_in[8]};
  const float* Wo = (const float*)d_in[9];
  float* out = (float*)d_out;
  char* ws = (char*)d_ws;

  // workspace layout (bytes):
  // [0, 32M): 8 x f16 PV partials (4 MB each)
  // [32M, 64M): xh f16 (32 MB)
  // [64M, 88M): q1h,q2h,k1h,k2h,vh,vt (4 MB each); then Wth (1.25M), Woth (0.25M), P (69M)
  const size_t OFF_XH   = 33554432;
  const size_t OFF_H    = OFF_XH + 33554432;
  const size_t OFF_WTH  = OFF_H + 6 * 4194304;
  const size_t OFF_WOTH = OFF_WTH + 1310720;
  const size_t OFF_P    = OFF_WOTH + 262144;
  f16*   obase = (f16*)(ws + 0);
  f16*   xh   = (f16*)(ws + OFF_XH);
  f16*   q1h  = (f16*)(ws + OFF_H + 0 * 4194304);
  f16*   q2h  = (f16*)(ws + OFF_H + 1 * 4194304);
  f16*   k1h  = (f16*)(ws + OFF_H + 2 * 4194304);
  f16*   k2h  = (f16*)(ws + OFF_H + 3 * 4194304);
  f16*   vh   = (f16*)(ws + OFF_H + 4 * 4194304);
  f16*   vt   = (f16*)(ws + OFF_H + 5 * 4194304);
  f16*   Wth  = (f16*)(ws + OFF_WTH);
  f16*   Woth = (f16*)(ws + OFF_WOTH);
  f16*   P    = (f16*)(ws + OFF_P);

  // 1) prep: x cvt + all weight transposes (one dispatch)
  k_prep<<<17152, 256, 0, stream>>>(x, W[0], W[1], W[2], W[3], W[4], Wo, xh, Wth, Woth);
  // 2) projections (f16 A, XCD-grouped) with fused RoPE epilogue  [round-5 proven form]
  k_proj<<<640, 256, 0, stream>>>(xh, Wth, cp, sp, q1h, q2h, k1h, k2h, vh);
  // 3) V transpose
  k_vtrans16<<<dim3(512, 4), 256, 0, stream>>>(vh, vt);
  // 4) S-phase (packed triangular P)
  k_s<<<2112, 256, 0, stream>>>(q1h, q2h, k1h, k2h, P);
  // 5) PV-phase (split-K f16 partials, 512-key chunks)
  k_pv<<<576, 256, 0, stream>>>(P, vt, obase);
  // 6) output projection with fused partial combine
  k_gout<<<dim3(8, 128), 256, 0, stream>>>(obase, Woth, out);
}

// Round 9
// 132.035 us; speedup vs baseline: 1.2471x; 1.1296x over previous
//
#include <hip/hip_runtime.h>
#include <stdint.h>
#include <stddef.h>

typedef _Float16 f16;
typedef __attribute__((ext_vector_type(8))) _Float16 f16x8;
typedef __attribute__((ext_vector_type(4))) _Float16 f16x4;
typedef __attribute__((ext_vector_type(16))) float f32x16;
typedef __attribute__((ext_vector_type(4))) float floatx4;

#define MFMA(a, b, c) __builtin_amdgcn_mfma_f32_32x32x16_f16((a), (b), (c), 0, 0, 0)

typedef const __attribute__((address_space(1))) void gvoid_t;
typedef __attribute__((address_space(3))) void svoid_t;

__device__ __forceinline__ void gload_lds16(const void* g, void* l) {
  // wave-uniform LDS base; HW writes lane's 16B at base + lane*16
  __builtin_amdgcn_global_load_lds((gvoid_t*)g, (svoid_t*)l, 16, 0, 0);
}

// ---------------- prep: x fp32->f16 cvt + all weight transposes, one dispatch ----------------
__global__ __launch_bounds__(256) void k_prep(const float* __restrict__ x,
                                              const float* __restrict__ W0,
                                              const float* __restrict__ W1,
                                              const float* __restrict__ W2,
                                              const float* __restrict__ W3,
                                              const float* __restrict__ W4,
                                              const float* __restrict__ Wo,
                                              f16* __restrict__ xh,
                                              f16* __restrict__ Wth,
                                              f16* __restrict__ Woth) {
  __shared__ float t[32][33];
  int bid = blockIdx.x;
  if (bid < 16384) {  // x -> f16, vectorized
    int i = bid * 256 + threadIdx.x;
    floatx4 v = ((const floatx4*)x)[i];
    f16x4 o;
    o[0] = (f16)v[0]; o[1] = (f16)v[1]; o[2] = (f16)v[2]; o[3] = (f16)v[3];
    ((f16x4*)xh)[i] = o;
    return;
  }
  const float* W;
  f16* Wt;
  int K, N, k0, n0;
  if (bid < 17024) {
    int b2 = bid - 16384;
    int w = b2 >> 7, tt = b2 & 127;
    W = (w == 0) ? W0 : (w == 1) ? W1 : (w == 2) ? W2 : (w == 3) ? W3 : W4;
    Wt = Wth + (size_t)w * 128 * 1024;
    K = 1024; N = 128;
    k0 = (tt & 31) * 32; n0 = (tt >> 5) * 32;
  } else {
    int tt = bid - 17024;
    W = Wo; Wt = Woth;
    K = 128; N = 1024;
    k0 = (tt & 3) * 32; n0 = (tt >> 2) * 32;
  }
  int tx = threadIdx.x & 31, ty = threadIdx.x >> 5;  // 32 x 8
#pragma unroll
  for (int i = 0; i < 4; ++i)
    t[ty + 8 * i][tx] = W[(size_t)(k0 + ty + 8 * i) * N + n0 + tx];
  __syncthreads();
#pragma unroll
  for (int i = 0; i < 4; ++i)
    Wt[(size_t)(n0 + ty + 8 * i) * K + k0 + tx] = (f16)t[tx][ty + 8 * i];
}

// ---------------- projection GEMM (f16 A via gload_lds), XCD-group swizzle, fused RoPE ----------------
__global__ __launch_bounds__(256, 2) void k_proj(const f16* __restrict__ A,
                                                 const f16* __restrict__ Bt,
                                                 const float* __restrict__ cosp,
                                                 const float* __restrict__ sinp,
                                                 f16* __restrict__ q1h, f16* __restrict__ q2h,
                                                 f16* __restrict__ k1h, f16* __restrict__ k2h,
                                                 f16* __restrict__ vh) {
  __shared__ __align__(16) f16 As[128 * 64];
  __shared__ __align__(16) f16 Bs[128 * 64];
  int bid = blockIdx.x;
  int c8 = bid & 7, t = bid >> 3;          // t in 0..79
  int n0 = t % 5;                          // matrix id
  int m0 = (c8 + 8 * (t / 5)) * 128;       // row panel: 5 consecutive turns of XCD c8
  int tid = threadIdx.x;
  int wave = tid >> 6, lane = tid & 63;
  int wm = wave * 32;
  int rl = lane & 31, h = lane >> 5;
  int srow = lane >> 3, sslot = lane & 7;
  const f16* Bmat = Bt + (size_t)n0 * 128 * 1024;

  f32x16 acc[4];
#pragma unroll
  for (int nb = 0; nb < 4; ++nb)
#pragma unroll
    for (int r = 0; r < 16; ++r) acc[nb][r] = 0.f;

  for (int k0 = 0; k0 < 1024; k0 += 64) {
    __syncthreads();
#pragma unroll
    for (int c = 0; c < 4; ++c) {
      int chunk = c * 4 + wave;
      int r = chunk * 8 + srow;
      int cb = sslot ^ (r & 7);
      gload_lds16(A + (size_t)(m0 + r) * 1024 + k0 + cb * 8, As + chunk * 512);
      gload_lds16(Bmat + (size_t)r * 1024 + k0 + cb * 8, Bs + chunk * 512);
    }
    __syncthreads();

#pragma unroll
    for (int kb = 0; kb < 4; ++kb) {
      int s = 2 * kb + h;
      int ra = wm + rl;
      f16x8 af = *(const f16x8*)(As + ra * 64 + (s ^ (ra & 7)) * 8);
      f16x8 bf[4];
#pragma unroll
      for (int nb = 0; nb < 4; ++nb) {
        int rb = nb * 32 + rl;
        bf[nb] = *(const f16x8*)(Bs + rb * 64 + (s ^ (rb & 7)) * 8);
      }
#pragma unroll
      for (int nb = 0; nb < 4; ++nb) acc[nb] = MFMA(af, bf[nb], acc[nb]);
    }
  }

  if (n0 == 4) {  // V: plain cvt store
#pragma unroll
    for (int r = 0; r < 16; ++r) {
      int irow = (r & 3) + 8 * (r >> 2) + 4 * h;
      int gr = m0 + wm + irow;
#pragma unroll
      for (int nb = 0; nb < 4; ++nb)
        vh[(size_t)gr * 128 + nb * 32 + rl] = (f16)acc[nb][r];
    }
  } else {
    f16* outp = (n0 == 0) ? q1h : (n0 == 1) ? q2h : (n0 == 2) ? k1h : k2h;
#pragma unroll
    for (int r = 0; r < 16; ++r) {
      int irow = (r & 3) + 8 * (r >> 2) + 4 * h;
      int gr = m0 + wm + irow;
      int s = gr & 4095;
#pragma unroll
      for (int nb = 0; nb < 2; ++nb) {
        int d = nb * 32 + rl;
        float c = cosp[s * 64 + d], sn = sinp[s * 64 + d];
        float a = acc[nb][r], bb = acc[nb + 2][r];
        outp[(size_t)gr * 128 + d]      = (f16)(a * c - bb * sn);
        outp[(size_t)gr * 128 + 64 + d] = (f16)(a * sn + bb * c);
      }
    }
  }
}

// ---------------- V transpose (f16): vh(16384x128) -> vt[b][d][s] ----------------
__global__ __launch_bounds__(256) void k_vtrans16(const f16* __restrict__ vh,
                                                  f16* __restrict__ vt) {
  __shared__ unsigned short t[32][33];
  int r0 = blockIdx.x * 32, d0 = blockIdx.y * 32;
  int tx = threadIdx.x & 31, ty = threadIdx.x >> 5;
#pragma unroll
  for (int i = 0; i < 4; ++i)
    t[ty + 8 * i][tx] = ((const unsigned short*)vh)[(size_t)(r0 + ty + 8 * i) * 128 + d0 + tx];
  __syncthreads();
  int b = r0 >> 12, s0 = r0 & 4095;
#pragma unroll
  for (int i = 0; i < 4; ++i)
    ((unsigned short*)vt)[((size_t)(b * 128 + d0 + ty + 8 * i)) * 4096 + s0 + tx] =
        t[tx][ty + 8 * i];
}

// ---------------- S-phase: P = mask(S1*S2)/128, packed lower-triangle tiles ----------------
__global__ __launch_bounds__(256, 2) void k_s(const f16* __restrict__ q1h,
                                              const f16* __restrict__ q2h,
                                              const f16* __restrict__ k1h,
                                              const f16* __restrict__ k2h,
                                              f16* __restrict__ P) {
  __shared__ __align__(16) f16 A1[128 * 64];
  __shared__ __align__(16) f16 A2[128 * 64];
  __shared__ __align__(16) f16 B1[128 * 64];
  __shared__ __align__(16) f16 B2[128 * 64];
  int bid0 = blockIdx.x;
  int bid = (bid0 & 7) * 264 + (bid0 >> 3);  // XCD-contiguous chunks (2112 = 8*264)
  int b = bid / 528, t = bid % 528;
  int i = (int)((sqrtf(8.f * t + 1.f) - 1.f) * 0.5f);
  if ((i + 1) * (i + 2) / 2 <= t) ++i;
  if (i * (i + 1) / 2 > t) --i;
  int j = t - i * (i + 1) / 2;

  int tid = threadIdx.x;
  int wave = tid >> 6, lane = tid & 63;
  int wm = (wave >> 1) * 64, wn = (wave & 1) * 64;
  int rl = lane & 31, h = lane >> 5;
  int srow = lane >> 3, sslot = lane & 7;
  size_t rowA = (size_t)b * 4096 + i * 128;
  size_t rowB = (size_t)b * 4096 + j * 128;

  f32x16 acc1[2][2], acc2[2][2];
#pragma unroll
  for (int mb = 0; mb < 2; ++mb)
#pragma unroll
    for (int nb = 0; nb < 2; ++nb)
#pragma unroll
      for (int r = 0; r < 16; ++r) { acc1[mb][nb][r] = 0.f; acc2[mb][nb][r] = 0.f; }

  for (int k0 = 0; k0 < 128; k0 += 64) {
    __syncthreads();
#pragma unroll
    for (int c = 0; c < 4; ++c) {
      int chunk = c * 4 + wave;
      int r = chunk * 8 + srow;
      int cb = sslot ^ (r & 7);
      gload_lds16(q1h + (rowA + r) * 128 + k0 + cb * 8, A1 + chunk * 512);
      gload_lds16(q2h + (rowA + r) * 128 + k0 + cb * 8, A2 + chunk * 512);
      gload_lds16(k1h + (rowB + r) * 128 + k0 + cb * 8, B1 + chunk * 512);
      gload_lds16(k2h + (rowB + r) * 128 + k0 + cb * 8, B2 + chunk * 512);
    }
    __syncthreads();

#pragma unroll
    for (int kb = 0; kb < 4; ++kb) {
      int s = 2 * kb + h;
      f16x8 a1f[2], a2f[2], b1f[2], b2f[2];
#pragma unroll
      for (int mb = 0; mb < 2; ++mb) {
        int r = wm + mb * 32 + rl;
        int off = r * 64 + (s ^ (r & 7)) * 8;
        a1f[mb] = *(const f16x8*)(A1 + off);
        a2f[mb] = *(const f16x8*)(A2 + off);
      }
#pragma unroll
      for (int nb = 0; nb < 2; ++nb) {
        int r = wn + nb * 32 + rl;
        int off = r * 64 + (s ^ (r & 7)) * 8;
        b1f[nb] = *(const f16x8*)(B1 + off);
        b2f[nb] = *(const f16x8*)(B2 + off);
      }
#pragma unroll
      for (int mb = 0; mb < 2; ++mb)
#pragma unroll
        for (int nb = 0; nb < 2; ++nb) {
          acc1[mb][nb] = MFMA(a1f[mb], b1f[nb], acc1[mb][nb]);
          acc2[mb][nb] = MFMA(a2f[mb], b2f[nb], acc2[mb][nb]);
        }
    }
  }

  f16* pt = P + ((size_t)b * 528 + t) * 16384;
  bool diag = (i == j);
#pragma unroll
  for (int mb = 0; mb < 2; ++mb)
#pragma unroll
    for (int nb = 0; nb < 2; ++nb)
#pragma unroll
      for (int r = 0; r < 16; ++r) {
        int row_l = wm + mb * 32 + (r & 3) + 8 * (r >> 2) + 4 * h;
        int col_l = wn + nb * 32 + rl;
        float p = acc1[mb][nb][r] * acc2[mb][nb][r] * (1.0f / 128.0f);
        if (diag && col_l > row_l) p = 0.f;
        pt[(size_t)row_l * 128 + col_l] = (f16)p;
      }
}

// ---------------- PV-phase: O_partial = P_packed * V^T, split-K over 512-key chunks ----------------
__global__ __launch_bounds__(256, 2) void k_pv(const f16* __restrict__ P,
                                               const f16* __restrict__ vt,
                                               f16* __restrict__ obase) {
  __shared__ __align__(16) f16 As[128 * 64];
  __shared__ __align__(16) f16 Bs[128 * 64];
  int bid = blockIdx.x;
  int b = bid / 144, c = bid % 144;
  int g = (int)((sqrtf(2.f * c + 1.f) - 1.f) * 0.5f);
  while (2 * (g + 1) * (g + 2) <= c) ++g;
  while (2 * g * (g + 1) > c) --g;
  int off = c - 2 * g * (g + 1);
  int qt = g * 4 + off / (g + 1);
  int s = off - (off / (g + 1)) * (g + 1);
  int tq = qt * (qt + 1) / 2;
  const f16* Pb = P + (size_t)b * 528 * 16384;
  const f16* vb = vt + (size_t)b * 128 * 4096;
  int kbase = s * 512;
  int kend = (qt + 1) * 128 < kbase + 512 ? (qt + 1) * 128 : kbase + 512;

  int tid = threadIdx.x;
  int wave = tid >> 6, lane = tid & 63;
  int wm = (wave >> 1) * 64, wn = (wave & 1) * 64;
  int rl = lane & 31, h = lane >> 5;
  int srow = lane >> 3, sslot = lane & 7;

  f32x16 acc[2][2];
#pragma unroll
  for (int mb = 0; mb < 2; ++mb)
#pragma unroll
    for (int nb = 0; nb < 2; ++nb)
#pragma unroll
      for (int r = 0; r < 16; ++r) acc[mb][nb][r] = 0.f;

  for (int k0 = kbase; k0 < kend; k0 += 64) {
    int jt = k0 >> 7, koff = k0 & 127;
    const f16* Pt = Pb + (size_t)(tq + jt) * 16384;
    __syncthreads();
#pragma unroll
    for (int c4 = 0; c4 < 4; ++c4) {
      int chunk = c4 * 4 + wave;
      int r = chunk * 8 + srow;
      int cb = sslot ^ (r & 7);
      gload_lds16(Pt + (size_t)r * 128 + koff + cb * 8, As + chunk * 512);
      gload_lds16(vb + (size_t)r * 4096 + k0 + cb * 8, Bs + chunk * 512);
    }
    __syncthreads();

#pragma unroll
    for (int kb = 0; kb < 4; ++kb) {
      int sidx = 2 * kb + h;
      f16x8 af[2], bf[2];
#pragma unroll
      for (int mb = 0; mb < 2; ++mb) {
        int r = wm + mb * 32 + rl;
        af[mb] = *(const f16x8*)(As + r * 64 + (sidx ^ (r & 7)) * 8);
      }
#pragma unroll
      for (int nb = 0; nb < 2; ++nb) {
        int r = wn + nb * 32 + rl;
        bf[nb] = *(const f16x8*)(Bs + r * 64 + (sidx ^ (r & 7)) * 8);
      }
#pragma unroll
      for (int mb = 0; mb < 2; ++mb)
#pragma unroll
        for (int nb = 0; nb < 2; ++nb)
          acc[mb][nb] = MFMA(af[mb], bf[nb], acc[mb][nb]);
    }
  }

  f16* op = obase + (size_t)s * 2097152;
#pragma unroll
  for (int mb = 0; mb < 2; ++mb)
#pragma unroll
    for (int nb = 0; nb < 2; ++nb)
#pragma unroll
      for (int r = 0; r < 16; ++r) {
        int gr = b * 4096 + qt * 128 + wm + mb * 32 + (r & 3) + 8 * (r >> 2) + 4 * h;
        op[(size_t)gr * 128 + wn + nb * 32 + rl] = (f16)acc[mb][nb][r];
      }
}

// ---------------- combine PV split partials -> f16 oh ----------------
// 262144 f16x8 groups (16384 rows x 16 groups). ns = qt/4+1 partials per row.
__global__ __launch_bounds__(256) void k_comb(const f16* __restrict__ obase,
                                              f16* __restrict__ oh) {
  int idx = blockIdx.x * 256 + threadIdx.x;
  int row = idx >> 4;
  int qt = (row & 4095) >> 7;
  int ns = (qt >> 2) + 1;
  float sum[8];
#pragma unroll
  for (int e = 0; e < 8; ++e) sum[e] = 0.f;
#pragma unroll
  for (int p = 0; p < 8; ++p) {
    if (p < ns) {
      f16x8 v = ((const f16x8*)(obase + (size_t)p * 2097152))[idx];
#pragma unroll
      for (int e = 0; e < 8; ++e) sum[e] += (float)v[e];
    }
  }
  f16x8 w;
#pragma unroll
  for (int e = 0; e < 8; ++e) w[e] = (f16)sum[e];
  ((f16x8*)oh)[idx] = w;
}

// ---------------- output projection: clean gload-staged GEMM ----------------
// C(16384x1024 fp32) = oh(16384x128 f16) * Woth(1024x128)^T
__global__ __launch_bounds__(256, 2) void k_gout(const f16* __restrict__ A,
                                                 const f16* __restrict__ Bt,
                                                 float* __restrict__ C) {
  __shared__ __align__(16) f16 As[128 * 64];
  __shared__ __align__(16) f16 Bs[128 * 64];
  int tid = threadIdx.x;
  int wave = tid >> 6, lane = tid & 63;
  int m0 = blockIdx.y * 128, n0 = blockIdx.x * 128;
  int wm = (wave >> 1) * 64, wn = (wave & 1) * 64;
  int rl = lane & 31, h = lane >> 5;
  int srow = lane >> 3, sslot = lane & 7;

  f32x16 acc[2][2];
#pragma unroll
  for (int mb = 0; mb < 2; ++mb)
#pragma unroll
    for (int nb = 0; nb < 2; ++nb)
#pragma unroll
      for (int r = 0; r < 16; ++r) acc[mb][nb][r] = 0.f;

  for (int k0 = 0; k0 < 128; k0 += 64) {
    __syncthreads();
#pragma unroll
    for (int c = 0; c < 4; ++c) {
      int chunk = c * 4 + wave;
      int r = chunk * 8 + srow;
      int cb = sslot ^ (r & 7);
      gload_lds16(A + (size_t)(m0 + r) * 128 + k0 + cb * 8, As + chunk * 512);
      gload_lds16(Bt + (size_t)(n0 + r) * 128 + k0 + cb * 8, Bs + chunk * 512);
    }
    __syncthreads();

#pragma unroll
    for (int kb = 0; kb < 4; ++kb) {
      int s = 2 * kb + h;
      f16x8 af[2], bf[2];
#pragma unroll
      for (int mb = 0; mb < 2; ++mb) {
        int r = wm + mb * 32 + rl;
        af[mb] = *(const f16x8*)(As + r * 64 + (s ^ (r & 7)) * 8);
      }
#pragma unroll
      for (int nb = 0; nb < 2; ++nb) {
        int r = wn + nb * 32 + rl;
        bf[nb] = *(const f16x8*)(Bs + r * 64 + (s ^ (r & 7)) * 8);
      }
#pragma unroll
      for (int mb = 0; mb < 2; ++mb)
#pragma unroll
        for (int nb = 0; nb < 2; ++nb)
          acc[mb][nb] = MFMA(af[mb], bf[nb], acc[mb][nb]);
    }
  }

#pragma unroll
  for (int mb = 0; mb < 2; ++mb)
#pragma unroll
    for (int nb = 0; nb < 2; ++nb)
#pragma unroll
      for (int r = 0; r < 16; ++r) {
        int i = m0 + wm + mb * 32 + (r & 3) + 8 * (r >> 2) + 4 * h;
        int j = n0 + wn + nb * 32 + rl;
        C[(size_t)i * 1024 + j] = acc[mb][nb][r];
      }
}

// ---------------- launch ----------------
extern "C" void kernel_launch(void* const* d_in, const int* in_sizes, int n_in,
                              void* d_out, int out_size, void* d_ws, size_t ws_size,
                              hipStream_t stream) {
  (void)in_sizes; (void)n_in; (void)out_size; (void)ws_size;
  const float* x  = (const float*)d_in[0];
  const float* cp = (const float*)d_in[1];
  const float* sp = (const float*)d_in[2];
  // d_in[3] = causal_mask (unused; mask computed analytically)
  const float* W[5] = {(const float*)d_in[4], (const float*)d_in[5], (const float*)d_in[6],
                       (const float*)d_in[7], (const float*)d_in[8]};
  const float* Wo = (const float*)d_in[9];
  float* out = (float*)d_out;
  char* ws = (char*)d_ws;

  // workspace layout (bytes):
  // [0, 32M): 8 x f16 PV partials (4 MB each)
  // [32M, 64M): xh f16 (32 MB)
  // [64M, 92M): q1h,q2h,k1h,k2h,vh,vt,oh (4 MB each); then Wth, Woth, P (69M)
  const size_t OFF_XH   = 33554432;
  const size_t OFF_H    = OFF_XH + 33554432;
  const size_t OFF_WTH  = OFF_H + 7 * 4194304;
  const size_t OFF_WOTH = OFF_WTH + 1310720;
  const size_t OFF_P    = OFF_WOTH + 262144;
  f16*   obase = (f16*)(ws + 0);
  f16*   xh   = (f16*)(ws + OFF_XH);
  f16*   q1h  = (f16*)(ws + OFF_H + 0 * 4194304);
  f16*   q2h  = (f16*)(ws + OFF_H + 1 * 4194304);
  f16*   k1h  = (f16*)(ws + OFF_H + 2 * 4194304);
  f16*   k2h  = (f16*)(ws + OFF_H + 3 * 4194304);
  f16*   vh   = (f16*)(ws + OFF_H + 4 * 4194304);
  f16*   vt   = (f16*)(ws + OFF_H + 5 * 4194304);
  f16*   oh   = (f16*)(ws + OFF_H + 6 * 4194304);
  f16*   Wth  = (f16*)(ws + OFF_WTH);
  f16*   Woth = (f16*)(ws + OFF_WOTH);
  f16*   P    = (f16*)(ws + OFF_P);

  // 1) prep: x cvt + all weight transposes (one dispatch)
  k_prep<<<17152, 256, 0, stream>>>(x, W[0], W[1], W[2], W[3], W[4], Wo, xh, Wth, Woth);
  // 2) projections (f16 A, XCD-grouped) with fused RoPE epilogue
  k_proj<<<640, 256, 0, stream>>>(xh, Wth, cp, sp, q1h, q2h, k1h, k2h, vh);
  // 3) V transpose
  k_vtrans16<<<dim3(512, 4), 256, 0, stream>>>(vh, vt);
  // 4) S-phase (packed triangular P)
  k_s<<<2112, 256, 0, stream>>>(q1h, q2h, k1h, k2h, P);
  // 5) PV-phase (split-K f16 partials, 512-key chunks)
  k_pv<<<576, 256, 0, stream>>>(P, vt, obase);
  // 6) combine partials -> f16 oh
  k_comb<<<1024, 256, 0, stream>>>(obase, oh);
  // 7) output projection (clean gload GEMM)
  k_gout<<<dim3(8, 128), 256, 0, stream>>>(oh, Woth, out);
}

// Round 11
// 130.938 us; speedup vs baseline: 1.2575x; 1.0084x over previous
//
#include <hip/hip_runtime.h>
#include <stdint.h>
#include <stddef.h>

typedef _Float16 f16;
typedef __attribute__((ext_vector_type(8))) _Float16 f16x8;
typedef __attribute__((ext_vector_type(4))) _Float16 f16x4;
typedef __attribute__((ext_vector_type(16))) float f32x16;
typedef __attribute__((ext_vector_type(4))) float floatx4;

#define MFMA(a, b, c) __builtin_amdgcn_mfma_f32_32x32x16_f16((a), (b), (c), 0, 0, 0)

typedef const __attribute__((address_space(1))) void gvoid_t;
typedef __attribute__((address_space(3))) void svoid_t;

__device__ __forceinline__ void gload_lds16(const void* g, void* l) {
  // wave-uniform LDS base; HW writes lane's 16B at base + lane*16
  __builtin_amdgcn_global_load_lds((gvoid_t*)g, (svoid_t*)l, 16, 0, 0);
}

// ---------------- prep: x fp32->f16 cvt + all weight transposes, one dispatch ----------------
__global__ __launch_bounds__(256) void k_prep(const float* __restrict__ x,
                                              const float* __restrict__ W0,
                                              const float* __restrict__ W1,
                                              const float* __restrict__ W2,
                                              const float* __restrict__ W3,
                                              const float* __restrict__ W4,
                                              const float* __restrict__ Wo,
                                              f16* __restrict__ xh,
                                              f16* __restrict__ Wth,
                                              f16* __restrict__ Woth) {
  __shared__ float t[32][33];
  int bid = blockIdx.x;
  if (bid < 16384) {  // x -> f16, vectorized
    int i = bid * 256 + threadIdx.x;
    floatx4 v = ((const floatx4*)x)[i];
    f16x4 o;
    o[0] = (f16)v[0]; o[1] = (f16)v[1]; o[2] = (f16)v[2]; o[3] = (f16)v[3];
    ((f16x4*)xh)[i] = o;
    return;
  }
  const float* W;
  f16* Wt;
  int K, N, k0, n0;
  if (bid < 17024) {
    int b2 = bid - 16384;
    int w = b2 >> 7, tt = b2 & 127;
    W = (w == 0) ? W0 : (w == 1) ? W1 : (w == 2) ? W2 : (w == 3) ? W3 : W4;
    Wt = Wth + (size_t)w * 128 * 1024;
    K = 1024; N = 128;
    k0 = (tt & 31) * 32; n0 = (tt >> 5) * 32;
  } else {
    int tt = bid - 17024;
    W = Wo; Wt = Woth;
    K = 128; N = 1024;
    k0 = (tt & 3) * 32; n0 = (tt >> 2) * 32;
  }
  int tx = threadIdx.x & 31, ty = threadIdx.x >> 5;  // 32 x 8
#pragma unroll
  for (int i = 0; i < 4; ++i)
    t[ty + 8 * i][tx] = W[(size_t)(k0 + ty + 8 * i) * N + n0 + tx];
  __syncthreads();
#pragma unroll
  for (int i = 0; i < 4; ++i)
    Wt[(size_t)(n0 + ty + 8 * i) * K + k0 + tx] = (f16)t[tx][ty + 8 * i];
}

// ---------------- projection GEMM (f16 A via gload_lds), XCD-group swizzle, fused RoPE ----------------
// Round-9 proven form: single-buffer stage -> barrier -> compute. Deterministic.
__global__ __launch_bounds__(256, 2) void k_proj(const f16* __restrict__ A,
                                                 const f16* __restrict__ Bt,
                                                 const float* __restrict__ cosp,
                                                 const float* __restrict__ sinp,
                                                 f16* __restrict__ q1h, f16* __restrict__ q2h,
                                                 f16* __restrict__ k1h, f16* __restrict__ k2h,
                                                 f16* __restrict__ vh) {
  __shared__ __align__(16) f16 As[128 * 64];
  __shared__ __align__(16) f16 Bs[128 * 64];
  int bid = blockIdx.x;
  int c8 = bid & 7, t = bid >> 3;          // t in 0..79
  int n0 = t % 5;                          // matrix id
  int m0 = (c8 + 8 * (t / 5)) * 128;       // row panel: 5 consecutive turns of XCD c8
  int tid = threadIdx.x;
  int wave = tid >> 6, lane = tid & 63;
  int wm = wave * 32;
  int rl = lane & 31, h = lane >> 5;
  int srow = lane >> 3, sslot = lane & 7;
  const f16* Bmat = Bt + (size_t)n0 * 128 * 1024;

  f32x16 acc[4];
#pragma unroll
  for (int nb = 0; nb < 4; ++nb)
#pragma unroll
    for (int r = 0; r < 16; ++r) acc[nb][r] = 0.f;

  for (int k0 = 0; k0 < 1024; k0 += 64) {
    __syncthreads();
#pragma unroll
    for (int c = 0; c < 4; ++c) {
      int chunk = c * 4 + wave;
      int r = chunk * 8 + srow;
      int cb = sslot ^ (r & 7);
      gload_lds16(A + (size_t)(m0 + r) * 1024 + k0 + cb * 8, As + chunk * 512);
      gload_lds16(Bmat + (size_t)r * 1024 + k0 + cb * 8, Bs + chunk * 512);
    }
    __syncthreads();

#pragma unroll
    for (int kb = 0; kb < 4; ++kb) {
      int s = 2 * kb + h;
      int ra = wm + rl;
      f16x8 af = *(const f16x8*)(As + ra * 64 + (s ^ (ra & 7)) * 8);
      f16x8 bf[4];
#pragma unroll
      for (int nb = 0; nb < 4; ++nb) {
        int rb = nb * 32 + rl;
        bf[nb] = *(const f16x8*)(Bs + rb * 64 + (s ^ (rb & 7)) * 8);
      }
#pragma unroll
      for (int nb = 0; nb < 4; ++nb) acc[nb] = MFMA(af, bf[nb], acc[nb]);
    }
  }

  if (n0 == 4) {  // V: plain cvt store
#pragma unroll
    for (int r = 0; r < 16; ++r) {
      int irow = (r & 3) + 8 * (r >> 2) + 4 * h;
      int gr = m0 + wm + irow;
#pragma unroll
      for (int nb = 0; nb < 4; ++nb)
        vh[(size_t)gr * 128 + nb * 32 + rl] = (f16)acc[nb][r];
    }
  } else {
    f16* outp = (n0 == 0) ? q1h : (n0 == 1) ? q2h : (n0 == 2) ? k1h : k2h;
#pragma unroll
    for (int r = 0; r < 16; ++r) {
      int irow = (r & 3) + 8 * (r >> 2) + 4 * h;
      int gr = m0 + wm + irow;
      int s = gr & 4095;
#pragma unroll
      for (int nb = 0; nb < 2; ++nb) {
        int d = nb * 32 + rl;
        float c = cosp[s * 64 + d], sn = sinp[s * 64 + d];
        float a = acc[nb][r], bb = acc[nb + 2][r];
        outp[(size_t)gr * 128 + d]      = (f16)(a * c - bb * sn);
        outp[(size_t)gr * 128 + 64 + d] = (f16)(a * sn + bb * c);
      }
    }
  }
}

// ---------------- S-phase + V transpose in one dispatch ----------------
// blocks [0, 2112): P = mask(S1*S2)/128 packed lower-triangle tiles
// blocks [2112, 4160): V transpose vh(16384x128) -> vt[b][d][s]
__global__ __launch_bounds__(256, 2) void k_s(const f16* __restrict__ q1h,
                                              const f16* __restrict__ q2h,
                                              const f16* __restrict__ k1h,
                                              const f16* __restrict__ k2h,
                                              const f16* __restrict__ vh,
                                              f16* __restrict__ vt,
                                              f16* __restrict__ P) {
  __shared__ __align__(16) f16 A1[128 * 64];
  __shared__ __align__(16) f16 A2[128 * 64];
  __shared__ __align__(16) f16 B1[128 * 64];
  __shared__ __align__(16) f16 B2[128 * 64];
  int bid0 = blockIdx.x;

  if (bid0 >= 2112) {  // ---- V transpose path (aliases A1 as its LDS buffer) ----
    unsigned short (*tt)[33] = (unsigned short(*)[33])A1;
    int bid2 = bid0 - 2112;
    int r0 = (bid2 & 511) * 32, d0 = (bid2 >> 9) * 32;
    int tx = threadIdx.x & 31, ty = threadIdx.x >> 5;
#pragma unroll
    for (int i = 0; i < 4; ++i)
      tt[ty + 8 * i][tx] = ((const unsigned short*)vh)[(size_t)(r0 + ty + 8 * i) * 128 + d0 + tx];
    __syncthreads();
    int b = r0 >> 12, s0 = r0 & 4095;
#pragma unroll
    for (int i = 0; i < 4; ++i)
      ((unsigned short*)vt)[((size_t)(b * 128 + d0 + ty + 8 * i)) * 4096 + s0 + tx] =
          tt[tx][ty + 8 * i];
    return;
  }

  int bid = (bid0 & 7) * 264 + (bid0 >> 3);  // XCD-contiguous chunks (2112 = 8*264)
  int b = bid / 528, t = bid % 528;
  int i = (int)((sqrtf(8.f * t + 1.f) - 1.f) * 0.5f);
  if ((i + 1) * (i + 2) / 2 <= t) ++i;
  if (i * (i + 1) / 2 > t) --i;
  int j = t - i * (i + 1) / 2;

  int tid = threadIdx.x;
  int wave = tid >> 6, lane = tid & 63;
  int wm = (wave >> 1) * 64, wn = (wave & 1) * 64;
  int rl = lane & 31, h = lane >> 5;
  int srow = lane >> 3, sslot = lane & 7;
  size_t rowA = (size_t)b * 4096 + i * 128;
  size_t rowB = (size_t)b * 4096 + j * 128;

  f32x16 acc1[2][2], acc2[2][2];
#pragma unroll
  for (int mb = 0; mb < 2; ++mb)
#pragma unroll
    for (int nb = 0; nb < 2; ++nb)
#pragma unroll
      for (int r = 0; r < 16; ++r) { acc1[mb][nb][r] = 0.f; acc2[mb][nb][r] = 0.f; }

  for (int k0 = 0; k0 < 128; k0 += 64) {
    __syncthreads();
#pragma unroll
    for (int c = 0; c < 4; ++c) {
      int chunk = c * 4 + wave;
      int r = chunk * 8 + srow;
      int cb = sslot ^ (r & 7);
      gload_lds16(q1h + (rowA + r) * 128 + k0 + cb * 8, A1 + chunk * 512);
      gload_lds16(q2h + (rowA + r) * 128 + k0 + cb * 8, A2 + chunk * 512);
      gload_lds16(k1h + (rowB + r) * 128 + k0 + cb * 8, B1 + chunk * 512);
      gload_lds16(k2h + (rowB + r) * 128 + k0 + cb * 8, B2 + chunk * 512);
    }
    __syncthreads();

#pragma unroll
    for (int kb = 0; kb < 4; ++kb) {
      int s = 2 * kb + h;
      f16x8 a1f[2], a2f[2], b1f[2], b2f[2];
#pragma unroll
      for (int mb = 0; mb < 2; ++mb) {
        int r = wm + mb * 32 + rl;
        int off = r * 64 + (s ^ (r & 7)) * 8;
        a1f[mb] = *(const f16x8*)(A1 + off);
        a2f[mb] = *(const f16x8*)(A2 + off);
      }
#pragma unroll
      for (int nb = 0; nb < 2; ++nb) {
        int r = wn + nb * 32 + rl;
        int off = r * 64 + (s ^ (r & 7)) * 8;
        b1f[nb] = *(const f16x8*)(B1 + off);
        b2f[nb] = *(const f16x8*)(B2 + off);
      }
#pragma unroll
      for (int mb = 0; mb < 2; ++mb)
#pragma unroll
        for (int nb = 0; nb < 2; ++nb) {
          acc1[mb][nb] = MFMA(a1f[mb], b1f[nb], acc1[mb][nb]);
          acc2[mb][nb] = MFMA(a2f[mb], b2f[nb], acc2[mb][nb]);
        }
    }
  }

  f16* pt = P + ((size_t)b * 528 + t) * 16384;
  bool diag = (i == j);
#pragma unroll
  for (int mb = 0; mb < 2; ++mb)
#pragma unroll
    for (int nb = 0; nb < 2; ++nb)
#pragma unroll
      for (int r = 0; r < 16; ++r) {
        int row_l = wm + mb * 32 + (r & 3) + 8 * (r >> 2) + 4 * h;
        int col_l = wn + nb * 32 + rl;
        float p = acc1[mb][nb][r] * acc2[mb][nb][r] * (1.0f / 128.0f);
        if (diag && col_l > row_l) p = 0.f;
        pt[(size_t)row_l * 128 + col_l] = (f16)p;
      }
}

// ---------------- PV-phase: O_partial = P_packed * V^T, split-K over 512-key chunks ----------------
__global__ __launch_bounds__(256, 2) void k_pv(const f16* __restrict__ P,
                                               const f16* __restrict__ vt,
                                               f16* __restrict__ obase) {
  __shared__ __align__(16) f16 As[128 * 64];
  __shared__ __align__(16) f16 Bs[128 * 64];
  int bid = blockIdx.x;
  int b = bid / 144, c = bid % 144;
  int g = (int)((sqrtf(2.f * c + 1.f) - 1.f) * 0.5f);
  while (2 * (g + 1) * (g + 2) <= c) ++g;
  while (2 * g * (g + 1) > c) --g;
  int off = c - 2 * g * (g + 1);
  int qt = g * 4 + off / (g + 1);
  int s = off - (off / (g + 1)) * (g + 1);
  int tq = qt * (qt + 1) / 2;
  const f16* Pb = P + (size_t)b * 528 * 16384;
  const f16* vb = vt + (size_t)b * 128 * 4096;
  int kbase = s * 512;
  int kend = (qt + 1) * 128 < kbase + 512 ? (qt + 1) * 128 : kbase + 512;

  int tid = threadIdx.x;
  int wave = tid >> 6, lane = tid & 63;
  int wm = (wave >> 1) * 64, wn = (wave & 1) * 64;
  int rl = lane & 31, h = lane >> 5;
  int srow = lane >> 3, sslot = lane & 7;

  f32x16 acc[2][2];
#pragma unroll
  for (int mb = 0; mb < 2; ++mb)
#pragma unroll
    for (int nb = 0; nb < 2; ++nb)
#pragma unroll
      for (int r = 0; r < 16; ++r) acc[mb][nb][r] = 0.f;

  for (int k0 = kbase; k0 < kend; k0 += 64) {
    int jt = k0 >> 7, koff = k0 & 127;
    const f16* Pt = Pb + (size_t)(tq + jt) * 16384;
    __syncthreads();
#pragma unroll
    for (int c4 = 0; c4 < 4; ++c4) {
      int chunk = c4 * 4 + wave;
      int r = chunk * 8 + srow;
      int cb = sslot ^ (r & 7);
      gload_lds16(Pt + (size_t)r * 128 + koff + cb * 8, As + chunk * 512);
      gload_lds16(vb + (size_t)r * 4096 + k0 + cb * 8, Bs + chunk * 512);
    }
    __syncthreads();

#pragma unroll
    for (int kb = 0; kb < 4; ++kb) {
      int sidx = 2 * kb + h;
      f16x8 af[2], bf[2];
#pragma unroll
      for (int mb = 0; mb < 2; ++mb) {
        int r = wm + mb * 32 + rl;
        af[mb] = *(const f16x8*)(As + r * 64 + (sidx ^ (r & 7)) * 8);
      }
#pragma unroll
      for (int nb = 0; nb < 2; ++nb) {
        int r = wn + nb * 32 + rl;
        bf[nb] = *(const f16x8*)(Bs + r * 64 + (sidx ^ (r & 7)) * 8);
      }
#pragma unroll
      for (int mb = 0; mb < 2; ++mb)
#pragma unroll
        for (int nb = 0; nb < 2; ++nb)
          acc[mb][nb] = MFMA(af[mb], bf[nb], acc[mb][nb]);
    }
  }

  f16* op = obase + (size_t)s * 2097152;
#pragma unroll
  for (int mb = 0; mb < 2; ++mb)
#pragma unroll
    for (int nb = 0; nb < 2; ++nb)
#pragma unroll
      for (int r = 0; r < 16; ++r) {
        int gr = b * 4096 + qt * 128 + wm + mb * 32 + (r & 3) + 8 * (r >> 2) + 4 * h;
        op[(size_t)gr * 128 + wn + nb * 32 + rl] = (f16)acc[mb][nb][r];
      }
}

// ---------------- combine PV split partials -> f16 oh ----------------
__global__ __launch_bounds__(256) void k_comb(const f16* __restrict__ obase,
                                              f16* __restrict__ oh) {
  int idx = blockIdx.x * 256 + threadIdx.x;
  int row = idx >> 4;
  int qt = (row & 4095) >> 7;
  int ns = (qt >> 2) + 1;
  float sum[8];
#pragma unroll
  for (int e = 0; e < 8; ++e) sum[e] = 0.f;
#pragma unroll
  for (int p = 0; p < 8; ++p) {
    if (p < ns) {
      f16x8 v = ((const f16x8*)(obase + (size_t)p * 2097152))[idx];
#pragma unroll
      for (int e = 0; e < 8; ++e) sum[e] += (float)v[e];
    }
  }
  f16x8 w;
#pragma unroll
  for (int e = 0; e < 8; ++e) w[e] = (f16)sum[e];
  ((f16x8*)oh)[idx] = w;
}

// ---------------- output projection: clean gload-staged GEMM ----------------
__global__ __launch_bounds__(256, 2) void k_gout(const f16* __restrict__ A,
                                                 const f16* __restrict__ Bt,
                                                 float* __restrict__ C) {
  __shared__ __align__(16) f16 As[128 * 64];
  __shared__ __align__(16) f16 Bs[128 * 64];
  int tid = threadIdx.x;
  int wave = tid >> 6, lane = tid & 63;
  int m0 = blockIdx.y * 128, n0 = blockIdx.x * 128;
  int wm = (wave >> 1) * 64, wn = (wave & 1) * 64;
  int rl = lane & 31, h = lane >> 5;
  int srow = lane >> 3, sslot = lane & 7;

  f32x16 acc[2][2];
#pragma unroll
  for (int mb = 0; mb < 2; ++mb)
#pragma unroll
    for (int nb = 0; nb < 2; ++nb)
#pragma unroll
      for (int r = 0; r < 16; ++r) acc[mb][nb][r] = 0.f;

  for (int k0 = 0; k0 < 128; k0 += 64) {
    __syncthreads();
#pragma unroll
    for (int c = 0; c < 4; ++c) {
      int chunk = c * 4 + wave;
      int r = chunk * 8 + srow;
      int cb = sslot ^ (r & 7);
      gload_lds16(A + (size_t)(m0 + r) * 128 + k0 + cb * 8, As + chunk * 512);
      gload_lds16(Bt + (size_t)(n0 + r) * 128 + k0 + cb * 8, Bs + chunk * 512);
    }
    __syncthreads();

#pragma unroll
    for (int kb = 0; kb < 4; ++kb) {
      int s = 2 * kb + h;
      f16x8 af[2], bf[2];
#pragma unroll
      for (int mb = 0; mb < 2; ++mb) {
        int r = wm + mb * 32 + rl;
        af[mb] = *(const f16x8*)(As + r * 64 + (s ^ (r & 7)) * 8);
      }
#pragma unroll
      for (int nb = 0; nb < 2; ++nb) {
        int r = wn + nb * 32 + rl;
        bf[nb] = *(const f16x8*)(Bs + r * 64 + (s ^ (r & 7)) * 8);
      }
#pragma unroll
      for (int mb = 0; mb < 2; ++mb)
#pragma unroll
        for (int nb = 0; nb < 2; ++nb)
          acc[mb][nb] = MFMA(af[mb], bf[nb], acc[mb][nb]);
    }
  }

#pragma unroll
  for (int mb = 0; mb < 2; ++mb)
#pragma unroll
    for (int nb = 0; nb < 2; ++nb)
#pragma unroll
      for (int r = 0; r < 16; ++r) {
        int i = m0 + wm + mb * 32 + (r & 3) + 8 * (r >> 2) + 4 * h;
        int j = n0 + wn + nb * 32 + rl;
        C[(size_t)i * 1024 + j] = acc[mb][nb][r];
      }
}

// ---------------- launch ----------------
extern "C" void kernel_launch(void* const* d_in, const int* in_sizes, int n_in,
                              void* d_out, int out_size, void* d_ws, size_t ws_size,
                              hipStream_t stream) {
  (void)in_sizes; (void)n_in; (void)out_size; (void)ws_size;
  const float* x  = (const float*)d_in[0];
  const float* cp = (const float*)d_in[1];
  const float* sp = (const float*)d_in[2];
  // d_in[3] = causal_mask (unused; mask computed analytically)
  const float* W[5] = {(const float*)d_in[4], (const float*)d_in[5], (const float*)d_in[6],
                       (const float*)d_in[7], (const float*)d_in[8]};
  const float* Wo = (const float*)d_in[9];
  float* out = (float*)d_out;
  char* ws = (char*)d_ws;

  // workspace layout (bytes):
  // [0, 32M): 8 x f16 PV partials (4 MB each)
  // [32M, 64M): xh f16 (32 MB)
  // [64M, 92M): q1h,q2h,k1h,k2h,vh,vt,oh (4 MB each); then Wth, Woth, P (69M)
  const size_t OFF_XH   = 33554432;
  const size_t OFF_H    = OFF_XH + 33554432;
  const size_t OFF_WTH  = OFF_H + 7 * 4194304;
  const size_t OFF_WOTH = OFF_WTH + 1310720;
  const size_t OFF_P    = OFF_WOTH + 262144;
  f16*   obase = (f16*)(ws + 0);
  f16*   xh   = (f16*)(ws + OFF_XH);
  f16*   q1h  = (f16*)(ws + OFF_H + 0 * 4194304);
  f16*   q2h  = (f16*)(ws + OFF_H + 1 * 4194304);
  f16*   k1h  = (f16*)(ws + OFF_H + 2 * 4194304);
  f16*   k2h  = (f16*)(ws + OFF_H + 3 * 4194304);
  f16*   vh   = (f16*)(ws + OFF_H + 4 * 4194304);
  f16*   vt   = (f16*)(ws + OFF_H + 5 * 4194304);
  f16*   oh   = (f16*)(ws + OFF_H + 6 * 4194304);
  f16*   Wth  = (f16*)(ws + OFF_WTH);
  f16*   Woth = (f16*)(ws + OFF_WOTH);
  f16*   P    = (f16*)(ws + OFF_P);

  // 1) prep: x cvt + all weight transposes (one dispatch)
  k_prep<<<17152, 256, 0, stream>>>(x, W[0], W[1], W[2], W[3], W[4], Wo, xh, Wth, Woth);
  // 2) projections (f16 A, XCD-grouped, single-buffer proven form) with fused RoPE
  k_proj<<<640, 256, 0, stream>>>(xh, Wth, cp, sp, q1h, q2h, k1h, k2h, vh);
  // 3) S-phase (packed triangular P) + V transpose, one dispatch
  k_s<<<4160, 256, 0, stream>>>(q1h, q2h, k1h, k2h, vh, vt, P);
  // 4) PV-phase (split-K f16 partials, 512-key chunks)
  k_pv<<<576, 256, 0, stream>>>(P, vt, obase);
  // 5) combine partials -> f16 oh
  k_comb<<<1024, 256, 0, stream>>>(obase, oh);
  // 6) output projection (clean gload GEMM)
  k_gout<<<dim3(8, 128), 256, 0, stream>>>(oh, Woth, out);
}